// Round 8
// baseline (279.254 us; speedup 1.0000x reference)
//
#include <hip/hip_runtime.h>
#include <hip/hip_bf16.h>
#include <stdint.h>

// NeuralFSM as integer FSM (exact). R21:
//  - mega split 2x: 500 blocks x 512 threads, one dst-HALF-bucket each.
//    2 blocks/CU (same 16 waves/CU) but INDEPENDENT grid-barrier participants:
//    while one block sits in barrier+state-reload (the ~6Kcy serial tail that
//    capped occupancy at 44%), the co-resident block's waves keep issuing
//    gather work. Cost: state reload runs twice per CU (+0.6Kcy), paid from
//    the recovered tail.
//  - p4: 250 blocks, one FULL bucket each (ob[CAPB]=110.6KB LDS, no bail);
//    sort key = ((dst>=200)<<8)|(src>>9) -> 512 bins; publishes half-split
//    point H to bar[HCNT_OFF+b]. src>>9 bins keep sigma windows at <=64 sPk
//    words (2/bank = free). Sigma suppressed on the 256-block straddling H
//    (a half-0 mega block must never see a half-1 edge -> mask OOB).
//  - barrier algorithm byte-identical to proven R15 form; only arrivals/line
//    10 -> 20 (500 blocks, 25 lines).
//  - R14/R15 kept: byte-addr packed csr word, x4 edge loads, sigma-permuted
//    coalesced writeback, s_sleep(1) spin, fixed-capacity buckets + cursor
//    reserve in build (unchanged).

#define NN 100000
#define EE 6400000
#define NCHARS 2048
#define ITERS 20

#define NBKT 250          // dst buckets (= p4 blocks)
#define MBLK 500          // mega blocks (2 per bucket)
#define NPB 400           // nodes per bucket
#define NPH 200           // nodes per half-bucket (per mega block)
#define WPS 12500         // words of packed state (NN/8)
#define X4N 3125          // WPS/4
#define CEDGE 12800       // edges per build block
#define NCHUNK 500        // build blocks
#define CAPB 27648        // fixed region capacity per bucket (mean 25600; 108*256)

// ---- bar region (words; lines 64B apart); zeroed by hipMemsetAsync ----
#define MEG_TOP     2080
#define CUR_OFF     3328                // cursor/count[250]
#define HCNT_OFF    3584                // half-split point H[250]
#define BAR_WORDS   4096                // 16 KB

typedef uint32_t u32x4 __attribute__((ext_vector_type(4)));

__device__ inline void mega_barrier(uint32_t* bar, int line, uint32_t epoch) {
    __syncthreads();                      // drains vmcnt: prior ops at coherence pt
    if (threadIdx.x == 0) {
        uint32_t old = atomicAdd(&bar[1664 + line * 16], 1u);
        if (old + 1u == 20u * epoch) {                      // 20 blocks per line
            uint32_t told = atomicAdd(&bar[MEG_TOP], 1u);
            if (told + 1u == 25u * epoch) {
                for (int r = 0; r < 25; ++r)
                    atomicExch(&bar[2112 + r * 16], epoch);
            }
        }
        while (__hip_atomic_load(&bar[2112 + line * 16], __ATOMIC_RELAXED,
                                 __HIP_MEMORY_SCOPE_AGENT) < epoch)
            __builtin_amdgcn_s_sleep(1);
    }
    __syncthreads();
}

// ---------- build: decode-stripe + count + reserve + scatter + lut write ----------
__global__ void __launch_bounds__(512) build_kernel(const int* __restrict__ src,
                                                    const int* __restrict__ dst,
                                                    const float* __restrict__ s0,
                                                    const float* __restrict__ T,
                                                    uint32_t* __restrict__ gPk0,
                                                    uint8_t* __restrict__ nextT,
                                                    uint32_t* __restrict__ csr,
                                                    uint32_t* __restrict__ bar) {
    __shared__ uint32_t stage[CEDGE];       // 51.2 KB
    __shared__ uint32_t cw[8][256];         // 8 KB: per-wave counts -> cursors
    __shared__ uint32_t scanb[512];
    __shared__ uint32_t loc[NBKT + 1];
    __shared__ uint32_t segoff[NBKT];
    __shared__ uint8_t  lut[CEDGE];         // 12.8 KB slot->bucket
    int t = threadIdx.x, w = t >> 6;
    int c = blockIdx.x;
    int e0 = c * CEDGE;
    const int4* ps4 = (const int4*)(src + e0);
    const int4* pd4 = (const int4*)(dst + e0);
    uint32_t* cursorG = bar + CUR_OFF;

    // --- decode stripe: block c packs nodes [c*200, c*200+200) -> 25 words ---
    if (t < 25) loc[t] = 0;
    __syncthreads();
    if (t < 200) {
        const float* row = s0 + ((size_t)c * 200 + t) * 8;
        int s = 0;
        #pragma unroll
        for (int q = 1; q < 8; ++q) if (row[q] > 0.5f) s = q;
        atomicOr(&loc[t >> 3], (uint32_t)s << ((t & 7) << 2));
    }
    __syncthreads();
    if (t < 25) gPk0[c * 25 + t] = loc[t];
    if (c < 4) {                             // nextT: 4 blocks x 512 entries
        const float* row = T + (c * 512 + t) * 8;
        int s = 0;
        #pragma unroll
        for (int q = 1; q < 8; ++q) if (row[q] > 0.5f) s = q;
        nextT[c * 512 + t] = (uint8_t)s;
    }
    __syncthreads();

    // --- count (int4 groups; edge group 4i..4i+3 -> wave (i%512)>>6) ---
    for (int i = t; i < 8 * 256; i += 512) ((uint32_t*)cw)[i] = 0;
    __syncthreads();
    for (int i = t; i < CEDGE / 4; i += 512) {
        int4 d = pd4[i];
        atomicAdd(&cw[w][d.x / NPB], 1u);
        atomicAdd(&cw[w][d.y / NPB], 1u);
        atomicAdd(&cw[w][d.z / NPB], 1u);
        atomicAdd(&cw[w][d.w / NPB], 1u);
    }
    __syncthreads();
    uint32_t tot = 0;
    if (t < NBKT) {
        #pragma unroll
        for (int w2 = 0; w2 < 8; ++w2) tot += cw[w2][t];
    }
    scanb[t] = tot;
    __syncthreads();
    for (int off = 1; off < 512; off <<= 1) {
        uint32_t x = (t >= off) ? scanb[t - off] : 0u;
        __syncthreads();
        scanb[t] += x;
        __syncthreads();
    }
    if (t < NBKT) {
        uint32_t excl = scanb[t] - tot;
        loc[t] = excl;
        uint32_t myStart = atomicAdd(&cursorG[t], tot);   // reserve slice
        segoff[t] = (uint32_t)t * CAPB + myStart - excl;
        uint32_t acc = excl;                 // counts -> per-wave stage cursors
        #pragma unroll
        for (int w2 = 0; w2 < 8; ++w2) {
            uint32_t cv = cw[w2][t];
            cw[w2][t] = acc;
            acc += cv;
        }
    }
    if (t == 0) loc[NBKT] = CEDGE;
    __syncthreads();
    // lut fill: thread b writes its own disjoint range
    for (int b = t; b < NBKT; b += 512) {
        uint32_t lo = loc[b], hi = loc[b + 1];
        for (uint32_t i = lo; i < hi; ++i) lut[i] = (uint8_t)b;
    }
    // scatter (IDENTICAL int4-group wave mapping as count phase)
    // pack: [31:18]=src>>3, [15:13]=src&7, [10:2]=dl*4
    //  -> wv>>16 = LDS byte addr of packed word; (wv>>11)&31 = nibble shift
    for (int i = t; i < CEDGE / 4; i += 512) {
        int4 d = pd4[i];
        int4 s = ps4[i];
        int bb; uint32_t dl, pos;
        bb = d.x / NPB; dl = (uint32_t)(d.x - bb * NPB);
        pos = atomicAdd(&cw[w][bb], 1u);
        stage[pos] = ((uint32_t)(s.x >> 3) << 18) | ((uint32_t)(s.x & 7) << 13) | (dl << 2);
        bb = d.y / NPB; dl = (uint32_t)(d.y - bb * NPB);
        pos = atomicAdd(&cw[w][bb], 1u);
        stage[pos] = ((uint32_t)(s.y >> 3) << 18) | ((uint32_t)(s.y & 7) << 13) | (dl << 2);
        bb = d.z / NPB; dl = (uint32_t)(d.z - bb * NPB);
        pos = atomicAdd(&cw[w][bb], 1u);
        stage[pos] = ((uint32_t)(s.z >> 3) << 18) | ((uint32_t)(s.z & 7) << 13) | (dl << 2);
        bb = d.w / NPB; dl = (uint32_t)(d.w - bb * NPB);
        pos = atomicAdd(&cw[w][bb], 1u);
        stage[pos] = ((uint32_t)(s.w >> 3) << 18) | ((uint32_t)(s.w & 7) << 13) | (dl << 2);
    }
    __syncthreads();
    // coalesced write via lut (2 LDS reads instead of 9-step binary search)
    for (int i = t; i < CEDGE; i += 512) {
        csr[segoff[lut[i]] + (uint32_t)i] = stage[i];
    }
}

// ---------- P4: full-bucket sort by (dst-half, src>>9); publishes H ----------
// Two-pass (histogram re-reads csr; L2-resident). Writeback coalesced and
// sigma-permuted per 256-block EXCEPT the block straddling the half boundary
// H and the partial tail (those stay identity so each mega half-block reads
// exactly its own half's edges).
__global__ void __launch_bounds__(512) p4_sortsrc(uint32_t* __restrict__ csr,
                                                  uint32_t* __restrict__ bar) {
    __shared__ uint32_t ob[CAPB];           // 110.6 KB
    __shared__ uint32_t binh[512];
    __shared__ uint32_t Hs;
    int t = threadIdx.x;
    int b = blockIdx.x;
    uint32_t n  = bar[CUR_OFF + b];
    if (n > CAPB) n = CAPB;                 // safety (build capacity assumption)
    uint32_t r0 = (uint32_t)b * CAPB;
    // key: bit8 = dst-local >= 200, bits 7:0 = src>>9 (<196)
    auto key = [](uint32_t w) {
        return (((w & 0x7FCu) >= 0x320u) ? 256u : 0u) | (w >> 24);
    };
    binh[t] = 0;
    __syncthreads();
    for (uint32_t i = t; i < n; i += 512) atomicAdd(&binh[key(csr[r0 + i])], 1u);
    __syncthreads();
    uint32_t v = binh[t];
    __syncthreads();
    for (int off = 1; off < 512; off <<= 1) {
        uint32_t x = (t >= off) ? binh[t - off] : 0u;
        __syncthreads();
        binh[t] += x;
        __syncthreads();
    }
    uint32_t excl = binh[t] - v;
    if (t == 255) {                          // inclusive sum of bins 0..255 = |half 0|
        Hs = binh[t];
        bar[HCNT_OFF + b] = binh[t];
    }
    __syncthreads();
    binh[t] = excl;                          // becomes cursor
    __syncthreads();
    for (uint32_t i = t; i < n; i += 512) {
        uint32_t w = csr[r0 + i];            // second read (L2-resident)
        uint32_t pos = atomicAdd(&binh[key(w)], 1u);
        ob[pos] = w;                         // LDS scatter (sorted order)
    }
    __syncthreads();
    uint32_t H = Hs;
    // permuted writeback: sigma within each FULL 256-block not straddling H
    for (uint32_t i = t; i < n; i += 512) {
        uint32_t bf = i & ~255u, bl = i | 255u;
        bool full = (bl < n);
        bool straddle = (bf < H) && (bl >= H);
        uint32_t s = (full && !straddle)
                   ? (bf | ((i & 3u) << 6) | ((i & 255u) >> 2))
                   : i;
        csr[r0 + i] = ob[s];
    }
}

// ---------- mega: 500 half-bucket blocks, fence-free persistent 20 iters ----------
__global__ void __launch_bounds__(512, 4) mega_kernel(const uint32_t* __restrict__ csr,
                                                      uint32_t* __restrict__ gPkA,
                                                      uint32_t* __restrict__ gPkB,
                                                      const uint8_t* __restrict__ nextT,
                                                      float* __restrict__ out,
                                                      uint32_t* __restrict__ bar) {
    __shared__ uint32_t sPk[WPS];           // 50 KB packed state (full)
    __shared__ uint32_t mask[NPH];          // 800 B
    __shared__ uint32_t packOwn[NPH / 8];   // 25 words
    __shared__ uint8_t  nT[NCHARS];
    __shared__ uint8_t  sown[NPH];
    int t = threadIdx.x;
    int j = blockIdx.x;
    int b = j >> 1, h = j & 1;
    uint32_t r0 = (uint32_t)b * CAPB;
    uint32_t n  = bar[CUR_OFF + b];          // bucket count (kernel-boundary coherent)
    uint32_t H  = bar[HCNT_OFF + b];         // half-split (written by p4)
    if (H > n) H = n;
    uint32_t lo = r0 + (h ? H : 0);
    uint32_t hi = r0 + (h ? n : H);
    uint32_t A0 = (lo + 255u) & ~255u;       // first sigma-aligned position
    if (A0 > hi) A0 = hi;
    uint32_t hoff = h ? 800u : 0u;           // mask byte-offset rebase
    const int line = j % 25;

    ((uint32_t*)nT)[t] = ((const uint32_t*)nextT)[t];   // 2048 B (512 thr)

    for (int p = 0; p < ITERS; ++p) {
        const uint32_t* curG = (p & 1) ? gPkB : gPkA;
        uint32_t*       nxtG = (p & 1) ? gPkA : gPkB;
        // coherent x4 reload of FULL packed state (bypasses stale L1/L2)
        {
            const u32x4* g4 = (const u32x4*)curG;
            int i0 = t, i1 = t + 512, i2 = t + 1024, i3 = t + 1536;
            int i4 = t + 2048, i5 = t + 2560, i6 = t + 3072;
            if (i6 > X4N - 1) i6 = X4N - 1;
            const u32x4 *q0 = g4 + i0, *q1 = g4 + i1, *q2 = g4 + i2, *q3 = g4 + i3;
            const u32x4 *q4 = g4 + i4, *q5 = g4 + i5, *q6 = g4 + i6;
            u32x4 a0, a1, a2, a3, a4, a5, a6;
            asm volatile(
                "global_load_dwordx4 %0, %7, off sc1\n\t"
                "global_load_dwordx4 %1, %8, off sc1\n\t"
                "global_load_dwordx4 %2, %9, off sc1\n\t"
                "global_load_dwordx4 %3, %10, off sc1\n\t"
                "global_load_dwordx4 %4, %11, off sc1\n\t"
                "global_load_dwordx4 %5, %12, off sc1\n\t"
                "global_load_dwordx4 %6, %13, off sc1\n\t"
                "s_waitcnt vmcnt(0)"
                : "=&v"(a0), "=&v"(a1), "=&v"(a2), "=&v"(a3),
                  "=&v"(a4), "=&v"(a5), "=&v"(a6)
                : "v"(q0), "v"(q1), "v"(q2), "v"(q3), "v"(q4), "v"(q5), "v"(q6)
                : "memory");
            u32x4* s4 = (u32x4*)sPk;
            s4[i0] = a0; s4[i1] = a1; s4[i2] = a2; s4[i3] = a3;
            s4[i4] = a4; s4[i5] = a5; s4[i6] = a6;
        }
        if (t < NPH) mask[t] = 0;
        if (t < NPH / 8) packOwn[t] = 0;
        __syncthreads();

        // gather: sigma-permuted storage -> subword j across the wave covers
        // 64 consecutive sorted edges (one src>>9 bin window -> <=2/bank)
        auto edge1 = [&](uint32_t wv) {
            uint32_t val = *(const uint32_t*)((const char*)sPk + (wv >> 16));
            uint32_t nb  = (val >> ((wv >> 11) & 31u)) & 7u;
            atomicOr((uint32_t*)((char*)mask + (wv & 0x7FCu) - hoff), 1u << nb);
        };
        // prologue: [lo, A0) identity-stored (straddle block portion)
        for (uint32_t i = lo + (uint32_t)t; i < A0; i += 512) edge1(csr[i]);
        // main: x4 over sigma-aligned region
        uint32_t e = A0 + ((uint32_t)t << 2);
        for (; e + 2051 < hi; e += 4096) {
            u32x4 wa = *(const u32x4*)(csr + e);
            u32x4 wb = *(const u32x4*)(csr + e + 2048);
            edge1(wa.x); edge1(wa.y); edge1(wa.z); edge1(wa.w);
            edge1(wb.x); edge1(wb.y); edge1(wb.z); edge1(wb.w);
        }
        for (; e + 3 < hi; e += 2048) {
            u32x4 wa = *(const u32x4*)(csr + e);
            edge1(wa.x); edge1(wa.y); edge1(wa.z); edge1(wa.w);
        }
        for (; e < hi; ++e) edge1(csr[e]);
        __syncthreads();

        // own-node update + nibble pack (this block's 200 nodes)
        if (t < NPH) {
            int node = b * NPB + h * NPH + t;
            uint32_t sOwn = (sPk[node >> 3] >> ((node & 7) << 2)) & 7u;
            uint8_t ns = nT[(mask[t] << 3) + sOwn];
            sown[t] = ns;
            atomicOr(&packOwn[t >> 3], (uint32_t)ns << ((t & 7) << 2));
        }
        __syncthreads();
        if (p < ITERS - 1) {
            if (t < NPH / 8)
                __hip_atomic_store(&nxtG[50 * b + 25 * h + t], packOwn[t],
                                   __ATOMIC_RELAXED, __HIP_MEMORY_SCOPE_AGENT);
            mega_barrier(bar, line, (uint32_t)(p + 1));
        }
    }
    __syncthreads();
    // one-hot output: 200 nodes * 8 floats, coalesced
    for (int f = t; f < NPH * 8; f += 512) {
        int node = f >> 3;
        out[(size_t)(b * NPB + h * NPH) * 8 + f] = ((f & 7) == (int)sown[node]) ? 1.f : 0.f;
    }
}

// ---------- fallback (tiny ws): R1 mask/atomicOr path ----------
__global__ void fb_decode(const float* __restrict__ s0, const float* __restrict__ T,
                          uint8_t* __restrict__ state, uint8_t* __restrict__ nextT,
                          uint32_t* __restrict__ mask) {
    int i = blockIdx.x * blockDim.x + threadIdx.x;
    if (i < NCHARS) {
        const float* row = T + i * 8;
        int t = 0;
        #pragma unroll
        for (int k = 1; k < 8; ++k) if (row[k] > 0.5f) t = k;
        nextT[i] = (uint8_t)t;
    }
    if (i < NN) {
        const float* row = s0 + i * 8;
        int s = 0;
        #pragma unroll
        for (int k = 1; k < 8; ++k) if (row[k] > 0.5f) s = k;
        state[i] = (uint8_t)s;
        mask[i] = 0u;
    }
}
__global__ void fb_edge(const int* __restrict__ src, const int* __restrict__ dst,
                        const uint8_t* __restrict__ state, uint32_t* __restrict__ mask) {
    int i = blockIdx.x * blockDim.x + threadIdx.x;
    int stride = gridDim.x * blockDim.x;
    for (int e = i; e < EE; e += stride) atomicOr(&mask[dst[e]], 1u << state[src[e]]);
}
__global__ void fb_update(uint8_t* __restrict__ state, uint32_t* __restrict__ mask,
                          const uint8_t* __restrict__ nextT) {
    int i = blockIdx.x * blockDim.x + threadIdx.x;
    if (i < NN) {
        uint32_t m = mask[i];
        state[i] = nextT[(m << 3) + state[i]];
        mask[i] = 0u;
    }
}
__global__ void fb_output(const uint8_t* __restrict__ state, float* __restrict__ out) {
    int i = blockIdx.x * blockDim.x + threadIdx.x;
    if (i < NN) {
        int s = state[i];
        float4 lo = make_float4(s == 0 ? 1.f : 0.f, s == 1 ? 1.f : 0.f,
                                s == 2 ? 1.f : 0.f, s == 3 ? 1.f : 0.f);
        float4 hi = make_float4(s == 4 ? 1.f : 0.f, s == 5 ? 1.f : 0.f,
                                s == 6 ? 1.f : 0.f, s == 7 ? 1.f : 0.f);
        float4* o = (float4*)(out + (size_t)i * 8);
        o[0] = lo;
        o[1] = hi;
    }
}

extern "C" void kernel_launch(void* const* d_in, const int* in_sizes, int n_in,
                              void* d_out, int out_size, void* d_ws, size_t ws_size,
                              hipStream_t stream) {
    const float* s0  = (const float*)d_in[0];
    const int*   ei  = (const int*)d_in[1];   // [2,E]: row0=src, row1=dst
    const float* T   = (const float*)d_in[2];
    float*       out = (float*)d_out;
    const int* src = ei;
    const int* dst = ei + EE;

    uint8_t* basep = (uint8_t*)d_ws;
    size_t off = 0;
    auto alloc = [&](size_t sz) -> void* {
        void* p = basep + off;
        off += (sz + 255) & ~(size_t)255;
        return p;
    };
    uint32_t* csr   = (uint32_t*)alloc(sizeof(uint32_t) * (size_t)NBKT * CAPB);
    uint8_t*  nextT = (uint8_t*)alloc(NCHARS);
    uint32_t* gPkA  = (uint32_t*)alloc(sizeof(uint32_t) * WPS);
    uint32_t* gPkB  = (uint32_t*)alloc(sizeof(uint32_t) * WPS);
    uint32_t* bar   = (uint32_t*)alloc(sizeof(uint32_t) * BAR_WORDS);
    bool have_ws = (off <= ws_size);

    if (have_ws) {
        hipMemsetAsync(bar, 0, sizeof(uint32_t) * BAR_WORDS, stream);
        build_kernel<<<NCHUNK, 512, 0, stream>>>(src, dst, s0, T, gPkA, nextT, csr, bar);
        p4_sortsrc<<<NBKT, 512, 0, stream>>>(csr, bar);
        mega_kernel<<<MBLK, 512, 0, stream>>>(csr, gPkA, gPkB, nextT, out, bar);
    } else {
        uint32_t* mask = (uint32_t*)d_ws;           // < 1 MB path
        uint8_t*  nT   = (uint8_t*)d_ws + 400128;
        uint8_t*  st   = (uint8_t*)d_ws + 402432;
        fb_decode<<<391, 256, 0, stream>>>(s0, T, st, nT, mask);
        for (int it = 0; it < ITERS; ++it) {
            fb_edge<<<2048, 256, 0, stream>>>(src, dst, st, mask);
            fb_update<<<391, 256, 0, stream>>>(st, mask, nT);
        }
        fb_output<<<391, 256, 0, stream>>>(st, out);
    }
}

// Round 9
// 246.881 us; speedup vs baseline: 1.1311x; 1.1311x over previous
//
#include <hip/hip_runtime.h>
#include <hip/hip_bf16.h>
#include <stdint.h>

// NeuralFSM as integer FSM (exact). R22:
//  - R21's 2x mega split regressed (same 16 waves/CU, doubled reload cost,
//    worse conflicts) -> REVERTED to R20's proven structure (best: 247.2us,
//    mega 117.2us). R17/R18/R19/R21 all show mega's gather+sync is at a
//    strong local optimum.
//  - micro-opt 1 (build): 512-wide Hillis-Steele scan (18 barriers) replaced
//    by wave-shuffle scan (3 barriers): per-wave __shfl_up scan -> 8 wave
//    sums -> offset add. ~3Kcy/block saved.
//  - micro-opt 2 (mega): mask/packOwn zeroing moved BEFORE the reload asm so
//    the ds_writes issue under global-load latency (asm ends in vmcnt(0)).
//  - R20 pieces kept verbatim: byte-addr packed csr word, x4 edge loads,
//    sigma-permuted writeback (subword j across wave = 64 consecutive sorted
//    edges -> conflict-free sPk reads), two-pass p4 (57KB LDS, 2 blocks/CU),
//    s_sleep(1) barrier spin, fixed-capacity buckets + cursor reserve,
//    fence-free 2-level grid barrier, coherent x4 state reload.

#define NN 100000
#define EE 6400000
#define NCHARS 2048
#define ITERS 20

#define NBKT 250          // dst buckets == mega blocks
#define NPB 400           // nodes per bucket
#define WPS 12500         // words of packed state (NN/8)
#define X4N 3125          // WPS/4
#define CEDGE 12800       // edges per build block
#define NCHUNK 500        // build blocks
#define CAPB 27648        // fixed region capacity per bucket (mean 25600; 108*256)
#define HCAP 13824        // p4 half-bucket LDS cap

// ---- bar region (words; lines 64B apart); zeroed by hipMemsetAsync ----
#define MEG_TOP     2080
#define CUR_OFF     3328                // cursor/count[250]
#define BAR_WORDS   4096                // 16 KB

typedef uint32_t u32x4 __attribute__((ext_vector_type(4)));

__device__ inline void mega_barrier(uint32_t* bar, int line, uint32_t epoch) {
    __syncthreads();                      // drains vmcnt: prior ops at coherence pt
    if (threadIdx.x == 0) {
        uint32_t old = atomicAdd(&bar[1664 + line * 16], 1u);
        if (old + 1u == 10u * epoch) {
            uint32_t told = atomicAdd(&bar[MEG_TOP], 1u);
            if (told + 1u == 25u * epoch) {
                for (int r = 0; r < 25; ++r)
                    atomicExch(&bar[2112 + r * 16], epoch);
            }
        }
        while (__hip_atomic_load(&bar[2112 + line * 16], __ATOMIC_RELAXED,
                                 __HIP_MEMORY_SCOPE_AGENT) < epoch)
            __builtin_amdgcn_s_sleep(1);
    }
    __syncthreads();
}

// ---------- build: decode-stripe + count + reserve + scatter + lut write ----------
__global__ void __launch_bounds__(512) build_kernel(const int* __restrict__ src,
                                                    const int* __restrict__ dst,
                                                    const float* __restrict__ s0,
                                                    const float* __restrict__ T,
                                                    uint32_t* __restrict__ gPk0,
                                                    uint8_t* __restrict__ nextT,
                                                    uint32_t* __restrict__ csr,
                                                    uint32_t* __restrict__ bar) {
    __shared__ uint32_t stage[CEDGE];       // 51.2 KB
    __shared__ uint32_t cw[8][256];         // 8 KB: per-wave counts -> cursors
    __shared__ uint32_t scanb[512];
    __shared__ uint32_t loc[NBKT + 1];
    __shared__ uint32_t segoff[NBKT];
    __shared__ uint8_t  lut[CEDGE];         // 12.8 KB slot->bucket
    int t = threadIdx.x, w = t >> 6;
    int c = blockIdx.x;
    int e0 = c * CEDGE;
    const int4* ps4 = (const int4*)(src + e0);
    const int4* pd4 = (const int4*)(dst + e0);
    uint32_t* cursorG = bar + CUR_OFF;

    // --- decode stripe: block c packs nodes [c*200, c*200+200) -> 25 words ---
    if (t < 25) loc[t] = 0;
    __syncthreads();
    if (t < 200) {
        const float* row = s0 + ((size_t)c * 200 + t) * 8;
        int s = 0;
        #pragma unroll
        for (int q = 1; q < 8; ++q) if (row[q] > 0.5f) s = q;
        atomicOr(&loc[t >> 3], (uint32_t)s << ((t & 7) << 2));
    }
    __syncthreads();
    if (t < 25) gPk0[c * 25 + t] = loc[t];
    if (c < 4) {                             // nextT: 4 blocks x 512 entries
        const float* row = T + (c * 512 + t) * 8;
        int s = 0;
        #pragma unroll
        for (int q = 1; q < 8; ++q) if (row[q] > 0.5f) s = q;
        nextT[c * 512 + t] = (uint8_t)s;
    }
    __syncthreads();

    // --- count (int4 groups; edge group 4i..4i+3 -> wave (i%512)>>6) ---
    for (int i = t; i < 8 * 256; i += 512) ((uint32_t*)cw)[i] = 0;
    __syncthreads();
    for (int i = t; i < CEDGE / 4; i += 512) {
        int4 d = pd4[i];
        atomicAdd(&cw[w][d.x / NPB], 1u);
        atomicAdd(&cw[w][d.y / NPB], 1u);
        atomicAdd(&cw[w][d.z / NPB], 1u);
        atomicAdd(&cw[w][d.w / NPB], 1u);
    }
    __syncthreads();
    uint32_t tot = 0;
    if (t < NBKT) {
        #pragma unroll
        for (int w2 = 0; w2 < 8; ++w2) tot += cw[w2][t];
    }
    // wave-shuffle exclusive scan over 512 threads (3 barriers, was 18)
    uint32_t x = tot;
    #pragma unroll
    for (int off = 1; off < 64; off <<= 1) {
        uint32_t y = __shfl_up(x, off, 64);
        if ((t & 63) >= off) x += y;
    }
    if ((t & 63) == 63) scanb[t >> 6] = x;   // per-wave total
    __syncthreads();
    if (t < 8) {
        uint32_t v = scanb[t];
        #pragma unroll
        for (int off = 1; off < 8; off <<= 1) {
            uint32_t y = __shfl_up(v, off, 8);
            if (t >= off) v += y;
        }
        scanb[t] = v;                        // inclusive wave-total prefix
    }
    __syncthreads();
    uint32_t incl = x + ((t >> 6) ? scanb[(t >> 6) - 1] : 0u);
    if (t < NBKT) {
        uint32_t excl = incl - tot;
        loc[t] = excl;
        uint32_t myStart = atomicAdd(&cursorG[t], tot);   // reserve slice
        segoff[t] = (uint32_t)t * CAPB + myStart - excl;
        uint32_t acc = excl;                 // counts -> per-wave stage cursors
        #pragma unroll
        for (int w2 = 0; w2 < 8; ++w2) {
            uint32_t cv = cw[w2][t];
            cw[w2][t] = acc;
            acc += cv;
        }
    }
    if (t == 0) loc[NBKT] = CEDGE;
    __syncthreads();
    // lut fill: thread b writes its own disjoint range
    for (int b = t; b < NBKT; b += 512) {
        uint32_t lo = loc[b], hi = loc[b + 1];
        for (uint32_t i = lo; i < hi; ++i) lut[i] = (uint8_t)b;
    }
    // scatter (IDENTICAL int4-group wave mapping as count phase)
    // pack: [31:18]=src>>3, [15:13]=src&7, [10:2]=dl*4
    //  -> wv>>16 = LDS byte addr of packed word; (wv>>11)&31 = nibble shift
    for (int i = t; i < CEDGE / 4; i += 512) {
        int4 d = pd4[i];
        int4 s = ps4[i];
        int bb; uint32_t dl, pos;
        bb = d.x / NPB; dl = (uint32_t)(d.x - bb * NPB);
        pos = atomicAdd(&cw[w][bb], 1u);
        stage[pos] = ((uint32_t)(s.x >> 3) << 18) | ((uint32_t)(s.x & 7) << 13) | (dl << 2);
        bb = d.y / NPB; dl = (uint32_t)(d.y - bb * NPB);
        pos = atomicAdd(&cw[w][bb], 1u);
        stage[pos] = ((uint32_t)(s.y >> 3) << 18) | ((uint32_t)(s.y & 7) << 13) | (dl << 2);
        bb = d.z / NPB; dl = (uint32_t)(d.z - bb * NPB);
        pos = atomicAdd(&cw[w][bb], 1u);
        stage[pos] = ((uint32_t)(s.z >> 3) << 18) | ((uint32_t)(s.z & 7) << 13) | (dl << 2);
        bb = d.w / NPB; dl = (uint32_t)(d.w - bb * NPB);
        pos = atomicAdd(&cw[w][bb], 1u);
        stage[pos] = ((uint32_t)(s.w >> 3) << 18) | ((uint32_t)(s.w & 7) << 13) | (dl << 2);
    }
    __syncthreads();
    // coalesced write via lut (2 LDS reads instead of 9-step binary search)
    for (int i = t; i < CEDGE; i += 512) {
        csr[segoff[lut[i]] + (uint32_t)i] = stage[i];
    }
}

// ---------- P4: bin-sort each half-bucket by src>>8 (two-pass, ~57KB LDS) ----------
// Pass A histograms csr directly (no staging buffer); pass B re-reads csr
// (L2-resident) and scatters into ob. Writeback is coalesced and sigma-
// PERMUTED per 256-edge block so mega's x4 gather reads 64 consecutive
// sorted edges per subword window (2-way bank pattern = free).
__global__ void __launch_bounds__(512) p4_sortsrc(uint32_t* __restrict__ csr,
                                                  const uint32_t* __restrict__ cntG) {
    __shared__ uint32_t ob[HCAP];           // 55.3 KB
    __shared__ uint32_t binh[512];
    int t = threadIdx.x;
    int j = blockIdx.x;
    int b = j >> 1, h = j & 1;
    uint32_t n  = cntG[b];
    uint32_t n1 = (((n + 1) >> 1) + 255u) & ~255u;   // split rounded UP to 256
    if (n1 > n) n1 = n;
    uint32_t r0 = (uint32_t)b * CAPB + (h ? n1 : 0); // 256-aligned (CAPB=108*256)
    uint32_t cnt = h ? n - n1 : n1;
    if (cnt == 0 || cnt > HCAP) return;     // leave unsorted (still correct)
    binh[t] = 0;
    __syncthreads();
    for (uint32_t i = t; i < cnt; i += 512) atomicAdd(&binh[csr[r0 + i] >> 23], 1u);  // src>>8
    __syncthreads();
    uint32_t v = binh[t];
    __syncthreads();
    for (int off = 1; off < 512; off <<= 1) {
        uint32_t x = (t >= off) ? binh[t - off] : 0u;
        __syncthreads();
        binh[t] += x;
        __syncthreads();
    }
    uint32_t excl = binh[t] - v;
    __syncthreads();
    binh[t] = excl;                          // becomes cursor
    __syncthreads();
    for (uint32_t i = t; i < cnt; i += 512) {
        uint32_t w = csr[r0 + i];            // second read (L2-resident)
        uint32_t pos = atomicAdd(&binh[w >> 23], 1u);
        ob[pos] = w;                         // LDS scatter (sorted order)
    }
    __syncthreads();
    // coalesced permuted writeback: storage i <- sorted sigma(i) within each
    // FULL 256-block; identity on the partial tail block (any order correct).
    for (uint32_t i = t; i < cnt; i += 512) {
        uint32_t s = ((i | 255u) < cnt)
                   ? ((i & ~255u) | ((i & 3u) << 6) | ((i & 255u) >> 2))
                   : i;
        csr[r0 + i] = ob[s];
    }
}

// ---------- mega: fence-free persistent 20 iterations (R15/R20 structure) ----------
__global__ void __launch_bounds__(1024) mega_kernel(const uint32_t* __restrict__ csr,
                                                    uint32_t* __restrict__ gPkA,
                                                    uint32_t* __restrict__ gPkB,
                                                    const uint8_t* __restrict__ nextT,
                                                    float* __restrict__ out,
                                                    uint32_t* __restrict__ bar) {
    __shared__ uint32_t sPk[WPS];           // 50 KB packed state
    __shared__ uint32_t mask[NPB];          // 1.6 KB
    __shared__ uint32_t packOwn[NPB / 8];
    __shared__ uint8_t  nT[NCHARS];
    __shared__ uint8_t  sown[NPB];
    int t = threadIdx.x;
    int b = blockIdx.x;
    uint32_t base = (uint32_t)b * CAPB;
    uint32_t end  = base + bar[CUR_OFF + b];     // bucket count (kernel-boundary coherent)

    if (t < 512) ((uint32_t*)nT)[t] = ((const uint32_t*)nextT)[t];   // 2048 B
    const int line = b % 25;

    for (int p = 0; p < ITERS; ++p) {
        const uint32_t* curG = (p & 1) ? gPkB : gPkA;
        uint32_t*       nxtG = (p & 1) ? gPkA : gPkB;
        // LDS zeroing first: ds_writes issue under the global-load latency
        if (t < NPB) mask[t] = 0;
        if (t < NPB / 8) packOwn[t] = 0;
        // coherent x4 reload of full packed state (bypasses stale L1/L2)
        {
            const u32x4* g4 = (const u32x4*)curG;
            int i0 = t, i1 = t + 1024, i2 = t + 2048;
            int i3 = t + 3072; if (i3 > X4N - 1) i3 = X4N - 1;
            const u32x4 *p0 = g4 + i0, *p1 = g4 + i1, *p2 = g4 + i2, *p3 = g4 + i3;
            u32x4 a0, a1, a2, a3;
            asm volatile(
                "global_load_dwordx4 %0, %4, off sc1\n\t"
                "global_load_dwordx4 %1, %5, off sc1\n\t"
                "global_load_dwordx4 %2, %6, off sc1\n\t"
                "global_load_dwordx4 %3, %7, off sc1\n\t"
                "s_waitcnt vmcnt(0)"
                : "=&v"(a0), "=&v"(a1), "=&v"(a2), "=&v"(a3)
                : "v"(p0), "v"(p1), "v"(p2), "v"(p3)
                : "memory");
            u32x4* s4 = (u32x4*)sPk;
            s4[i0] = a0; s4[i1] = a1; s4[i2] = a2; s4[i3] = a3;
        }
        __syncthreads();

        // gather: sigma-permuted storage -> subword j across the wave covers
        // 64 consecutive sorted edges (one src>>8 bin -> conflict-free)
        auto edge1 = [&](uint32_t wv) {
            uint32_t val = *(const uint32_t*)((const char*)sPk + (wv >> 16));
            uint32_t nb  = (val >> ((wv >> 11) & 31u)) & 7u;
            atomicOr((uint32_t*)((char*)mask + (wv & 0x7FCu)), 1u << nb);
        };
        uint32_t e = base + ((uint32_t)t << 2);
        for (; e + 4099 < end; e += 8192) {
            u32x4 wa = *(const u32x4*)(csr + e);
            u32x4 wb = *(const u32x4*)(csr + e + 4096);
            edge1(wa.x); edge1(wa.y); edge1(wa.z); edge1(wa.w);
            edge1(wb.x); edge1(wb.y); edge1(wb.z); edge1(wb.w);
        }
        for (; e + 3 < end; e += 4096) {
            u32x4 wa = *(const u32x4*)(csr + e);
            edge1(wa.x); edge1(wa.y); edge1(wa.z); edge1(wa.w);
        }
        for (; e < end; ++e) {
            edge1(csr[e]);
        }
        __syncthreads();

        // own-node update + nibble pack
        if (t < NPB) {
            int node = b * NPB + t;
            uint32_t sOwn = (sPk[node >> 3] >> ((node & 7) << 2)) & 7u;
            uint8_t ns = nT[(mask[t] << 3) + sOwn];
            sown[t] = ns;
            atomicOr(&packOwn[t >> 3], (uint32_t)ns << ((t & 7) << 2));
        }
        __syncthreads();
        if (p < ITERS - 1) {
            if (t < NPB / 8)
                __hip_atomic_store(&nxtG[(NPB / 8) * b + t], packOwn[t],
                                   __ATOMIC_RELAXED, __HIP_MEMORY_SCOPE_AGENT);
            mega_barrier(bar, line, (uint32_t)(p + 1));
        }
    }
    __syncthreads();
    // one-hot output: 400 nodes * 8 floats, coalesced
    for (int f = t; f < NPB * 8; f += 1024) {
        int node = f >> 3;
        out[(size_t)b * (NPB * 8) + f] = ((f & 7) == (int)sown[node]) ? 1.f : 0.f;
    }
}

// ---------- fallback (tiny ws): R1 mask/atomicOr path ----------
__global__ void fb_decode(const float* __restrict__ s0, const float* __restrict__ T,
                          uint8_t* __restrict__ state, uint8_t* __restrict__ nextT,
                          uint32_t* __restrict__ mask) {
    int i = blockIdx.x * blockDim.x + threadIdx.x;
    if (i < NCHARS) {
        const float* row = T + i * 8;
        int t = 0;
        #pragma unroll
        for (int k = 1; k < 8; ++k) if (row[k] > 0.5f) t = k;
        nextT[i] = (uint8_t)t;
    }
    if (i < NN) {
        const float* row = s0 + i * 8;
        int s = 0;
        #pragma unroll
        for (int k = 1; k < 8; ++k) if (row[k] > 0.5f) s = k;
        state[i] = (uint8_t)s;
        mask[i] = 0u;
    }
}
__global__ void fb_edge(const int* __restrict__ src, const int* __restrict__ dst,
                        const uint8_t* __restrict__ state, uint32_t* __restrict__ mask) {
    int i = blockIdx.x * blockDim.x + threadIdx.x;
    int stride = gridDim.x * blockDim.x;
    for (int e = i; e < EE; e += stride) atomicOr(&mask[dst[e]], 1u << state[src[e]]);
}
__global__ void fb_update(uint8_t* __restrict__ state, uint32_t* __restrict__ mask,
                          const uint8_t* __restrict__ nextT) {
    int i = blockIdx.x * blockDim.x + threadIdx.x;
    if (i < NN) {
        uint32_t m = mask[i];
        state[i] = nextT[(m << 3) + state[i]];
        mask[i] = 0u;
    }
}
__global__ void fb_output(const uint8_t* __restrict__ state, float* __restrict__ out) {
    int i = blockIdx.x * blockDim.x + threadIdx.x;
    if (i < NN) {
        int s = state[i];
        float4 lo = make_float4(s == 0 ? 1.f : 0.f, s == 1 ? 1.f : 0.f,
                                s == 2 ? 1.f : 0.f, s == 3 ? 1.f : 0.f);
        float4 hi = make_float4(s == 4 ? 1.f : 0.f, s == 5 ? 1.f : 0.f,
                                s == 6 ? 1.f : 0.f, s == 7 ? 1.f : 0.f);
        float4* o = (float4*)(out + (size_t)i * 8);
        o[0] = lo;
        o[1] = hi;
    }
}

extern "C" void kernel_launch(void* const* d_in, const int* in_sizes, int n_in,
                              void* d_out, int out_size, void* d_ws, size_t ws_size,
                              hipStream_t stream) {
    const float* s0  = (const float*)d_in[0];
    const int*   ei  = (const int*)d_in[1];   // [2,E]: row0=src, row1=dst
    const float* T   = (const float*)d_in[2];
    float*       out = (float*)d_out;
    const int* src = ei;
    const int* dst = ei + EE;

    uint8_t* basep = (uint8_t*)d_ws;
    size_t off = 0;
    auto alloc = [&](size_t sz) -> void* {
        void* p = basep + off;
        off += (sz + 255) & ~(size_t)255;
        return p;
    };
    uint32_t* csr   = (uint32_t*)alloc(sizeof(uint32_t) * (size_t)NBKT * CAPB);
    uint8_t*  nextT = (uint8_t*)alloc(NCHARS);
    uint32_t* gPkA  = (uint32_t*)alloc(sizeof(uint32_t) * WPS);
    uint32_t* gPkB  = (uint32_t*)alloc(sizeof(uint32_t) * WPS);
    uint32_t* bar   = (uint32_t*)alloc(sizeof(uint32_t) * BAR_WORDS);
    bool have_ws = (off <= ws_size);

    if (have_ws) {
        hipMemsetAsync(bar, 0, sizeof(uint32_t) * BAR_WORDS, stream);
        build_kernel<<<NCHUNK, 512, 0, stream>>>(src, dst, s0, T, gPkA, nextT, csr, bar);
        p4_sortsrc<<<NBKT * 2, 512, 0, stream>>>(csr, bar + CUR_OFF);
        mega_kernel<<<NBKT, 1024, 0, stream>>>(csr, gPkA, gPkB, nextT, out, bar);
    } else {
        uint32_t* mask = (uint32_t*)d_ws;           // < 1 MB path
        uint8_t*  nT   = (uint8_t*)d_ws + 400128;
        uint8_t*  st   = (uint8_t*)d_ws + 402432;
        fb_decode<<<391, 256, 0, stream>>>(s0, T, st, nT, mask);
        for (int it = 0; it < ITERS; ++it) {
            fb_edge<<<2048, 256, 0, stream>>>(src, dst, st, mask);
            fb_update<<<391, 256, 0, stream>>>(st, mask, nT);
        }
        fb_output<<<391, 256, 0, stream>>>(st, out);
    }
}